// Round 10
// baseline (999.702 us; speedup 1.0000x reference)
//
#include <hip/hip_runtime.h>
#include <hip/hip_bf16.h>
#include <stdint.h>

typedef __bf16 bf16_t;
typedef __bf16 bf16x4 __attribute__((ext_vector_type(4)));
typedef __bf16 bf16x8 __attribute__((ext_vector_type(8)));
typedef short s16x4 __attribute__((ext_vector_type(4)));
typedef float f32x4 __attribute__((ext_vector_type(4)));

static_assert(sizeof(bf16x8) == 16, "bf16x8 must be 16B");

#define MFMA_BF16(a, b, c) __builtin_amdgcn_mfma_f32_16x16x32_bf16((a), (b), (c), 0, 0, 0)

// 16x16x16 bf16 MFMA (r9-verified on HW: A[m=l15][k=quad*4+i],
// B[k=quad*4+i][n=l15], C/D row=quad*4+r col=l15)
__device__ __forceinline__ f32x4 mfma16(bf16x4 a, bf16x4 b, f32x4 c) {
#if __has_builtin(__builtin_amdgcn_mfma_f32_16x16x16bf16_1k)
  union { bf16x4 h; s16x4 s; } ua, ub;
  ua.h = a;
  ub.h = b;
  return __builtin_amdgcn_mfma_f32_16x16x16bf16_1k(ua.s, ub.s, c, 0, 0, 0);
#else
  f32x4 d = c;
  asm volatile("v_mfma_f32_16x16x16_bf16 %0, %1, %2, %0" : "+v"(d) : "v"(a), "v"(b));
  return d;
#endif
}

typedef const __attribute__((address_space(1))) void* gas_ptr;
typedef __attribute__((address_space(3))) void* las_ptr;

__device__ __forceinline__ void gload_lds16(const void* g, void* l) {
  __builtin_amdgcn_global_load_lds((gas_ptr)g, (las_ptr)l, 16, 0, 0);
}

#define NEG_BIG (-1.0e30f)

// ---------------------------------------------------------------------------
// fp32 -> bf16 convert
// ---------------------------------------------------------------------------
__global__ __launch_bounds__(256) void cvt_kernel(const float* __restrict__ src,
                                                  bf16_t* __restrict__ dst) {
  const int i = (blockIdx.x * 256 + threadIdx.x) * 4;
  const f32x4 v = *(const f32x4*)(src + i);
  bf16x4 o;
  o[0] = (bf16_t)v[0];
  o[1] = (bf16_t)v[1];
  o[2] = (bf16_t)v[2];
  o[3] = (bf16_t)v[3];
  *(bf16x4*)(dst + i) = o;
}

// ---------------------------------------------------------------------------
// GEMM (m97 structure): D[m][n] = sum_k A[m][k] * Bw[n][k]
// MODE 0: qkv epilogue -> q / k row-major (bf16), v transposed to vT[b][d][t]
// MODE 1: final epilogue -> o_f as FP32
// ---------------------------------------------------------------------------
template <int MODE>
__global__ __launch_bounds__(256, 2) void gemm_bt_kernel(
    const bf16_t* __restrict__ A, const bf16_t* __restrict__ Bw,
    bf16_t* __restrict__ o_q, bf16_t* __restrict__ o_k, bf16_t* __restrict__ o_vT,
    float* __restrict__ o_f) {
  constexpr int K = 512;
  __shared__ bf16_t As[128 * 32];
  __shared__ bf16_t Bs[128 * 32];

  const int tid = threadIdx.x;
  const int lane = tid & 63;
  const int wid = tid >> 6;
  const int quad = lane >> 4;
  const int l15 = lane & 15;
  const int wm = wid >> 1;
  const int wn = wid & 1;

  const int mt = blockIdx.x & 127;
  const int nt = blockIdx.x >> 7;
  const int row0 = mt * 128;
  const int col0 = nt * 128;

  f32x4 acc[4][4] = {};

  for (int kt = 0; kt < K; kt += 32) {
    __syncthreads();
#pragma unroll
    for (int rnd = 0; rnd < 2; rnd++) {
      const int e = (rnd * 256 + tid) * 8;
      const int r = e >> 5;
      const int c = e & 31;
      gload_lds16(A + (size_t)(row0 + r) * K + kt + c, As + e);
      gload_lds16(Bw + (size_t)(col0 + r) * K + kt + c, Bs + e);
    }
    __syncthreads();

    bf16x8 af[4], bfr[4];
#pragma unroll
    for (int i = 0; i < 4; i++)
      af[i] = *(const bf16x8*)(As + (wm * 64 + i * 16 + l15) * 32 + quad * 8);
#pragma unroll
    for (int i = 0; i < 4; i++)
      bfr[i] = *(const bf16x8*)(Bs + (wn * 64 + i * 16 + l15) * 32 + quad * 8);
#pragma unroll
    for (int mi = 0; mi < 4; mi++)
#pragma unroll
      for (int ni = 0; ni < 4; ni++)
        acc[mi][ni] = MFMA_BF16(af[mi], bfr[ni], acc[mi][ni]);
  }

#pragma unroll
  for (int mi = 0; mi < 4; mi++) {
    const int row = row0 + wm * 64 + mi * 16 + quad * 4;
#pragma unroll
    for (int ni = 0; ni < 4; ni++) {
      const int col = col0 + wn * 64 + ni * 16 + l15;
#pragma unroll
      for (int r = 0; r < 4; r++) {
        const int rr = row + r;
        if constexpr (MODE == 0) {
          const bf16_t bv = (bf16_t)acc[mi][ni][r];
          if (col < 512) {
            o_q[(size_t)rr * 512 + col] = bv;
          } else if (col < 1024) {
            o_k[(size_t)rr * 512 + (col - 512)] = bv;
          } else {
            const int bb = rr >> 12;
            const int t = rr & 4095;
            o_vT[((size_t)bb * 512 + (col - 1024)) * 4096 + t] = bv;
          }
        } else {
          o_f[(size_t)rr * 512 + col] = acc[mi][ni][r];
        }
      }
    }
  }
}

// ---------------------------------------------------------------------------
// Flash attention v4: r8 shell + r9 verified core.
//  - 4-wave blocks (256 thr), strip = 64 q-rows (wave owns 16), d-HALF split
//    (oacc 16 x f32x4). Grid = 4b x 64s x 2half = 512 blocks, heavy-first.
//  - KV tile = 16; Ks[2][16x512] double-buffered (32 KB TOTAL LDS), XOR
//    chunk swizzle; ONE __syncthreads per tile; next tile's global_load_lds
//    issued at iter top so the barrier's vmcnt(0) drain is compute-overlapped.
//  - S^T = K.Q^T (operand-swapped x32 MFMA): softmax per-lane (qrow=l15);
//    P stays in REGISTERS (already x16-MFMA A-layout) -> no LDS round-trip.
//  - V read DIRECTLY from global vT (B-frag = 4 contiguous elems of a vT
//    row = 8B loads, L1-resident tile) -> no Vs staging, no conflicts.
// ---------------------------------------------------------------------------
__global__ __launch_bounds__(256, 2) void attn_kernel(
    const bf16_t* __restrict__ q, const bf16_t* __restrict__ k,
    const bf16_t* __restrict__ vT, bf16_t* __restrict__ o) {
  __shared__ bf16_t Ks[2][16 * 512];  // 2 x 16 KB, chunk-XOR swizzled

  const int tid = threadIdx.x;
  const int lane = tid & 63;
  const int wid = tid >> 6;
  const int quad = lane >> 4;
  const int l15 = lane & 15;

  const int bid = blockIdx.x;     // 0..511
  const int half = bid & 1;       // output-d half
  const int b = (bid >> 1) & 3;   // batch
  const int s = 63 - (bid >> 3);  // strip (64 rows), heavy-first
  const int t0 = s * 64 + wid * 16;

  const float scale = 0.044194173824159216f;  // 1/sqrt(512)
  const bf16_t* kbase = k + (size_t)b * 4096 * 512;
  const bf16_t* vbase = vT + ((size_t)b * 512 + half * 256) * 4096;

  // Q B-fragments (for S^T): lane holds q[t0+l15][kk*32+quad*8 .. +7]
  bf16x8 qf[16];
  {
    const bf16_t* qp = q + ((size_t)(b * 4096 + t0 + l15)) * 512 + quad * 8;
#pragma unroll
    for (int kk = 0; kk < 16; kk++) qf[kk] = *(const bf16x8*)(qp + kk * 32);
  }

  f32x4 oacc[16] = {};  // oacc[dt][rr] = O[qrow=quad*4+rr][d=half*256+dt*16+l15]
  float mrow = NEG_BIG, lrow = 0.0f;

  const int jsteps = 4 * s + 4;  // block-uniform KV-16 tiles
  const int jcomp = 4 * s + wid; // this wave's last active tile

  // prologue: stage tile 0 -> buf 0 (16 KB: 4 rounds x 256 thr x 16B)
#pragma unroll
  for (int rnd = 0; rnd < 4; rnd++) {
    const int ch = rnd * 256 + tid;
    const int kr = ch >> 6;
    const int gc = (ch & 63) ^ (kr & 7);
    gload_lds16(kbase + (size_t)kr * 512 + gc * 8, &Ks[0][ch * 8]);
  }
  __syncthreads();

  const int sbase = (lane & 48) + ((lane & 48) >> 2);  // lane w/ l15=quad*4

  for (int j = 0; j < jsteps; j++) {
    const int buf = j & 1;
    // issue next tile's staging FIRST (drained by the end-of-iter barrier,
    // overlapped by this iter's compute)
    if (j + 1 < jsteps) {
      const bf16_t* kg = kbase + (size_t)(j + 1) * 16 * 512;
#pragma unroll
      for (int rnd = 0; rnd < 4; rnd++) {
        const int ch = rnd * 256 + tid;
        const int kr = ch >> 6;
        const int gc = (ch & 63) ^ (kr & 7);
        gload_lds16(kg + (size_t)kr * 512 + gc * 8, &Ks[buf ^ 1][ch * 8]);
      }
    }

    if (j <= jcomp) {
      // ---- S^T[kv16 x qrow16] = K . Q^T (swizzled Ks reads)
      f32x4 sT = {};
      const bf16_t* krow = &Ks[buf][l15 * 512];
      const int sw = l15 & 7;
#pragma unroll
      for (int kk = 0; kk < 16; kk++) {
        const bf16x8 kf = *(const bf16x8*)(krow + ((kk * 4 + quad) ^ sw) * 8);
        sT = MFMA_BF16(kf, qf[kk], sT);  // A=K, B=Q -> D=S^T
      }
      // ---- mask + inf-free online softmax (state per qrow = l15)
      const int qr = t0 + l15;
      float vv[4];
#pragma unroll
      for (int r = 0; r < 4; r++) {
        const int kvg = j * 16 + quad * 4 + r;
        vv[r] = (kvg <= qr) ? sT[r] * scale : NEG_BIG;
      }
      float mx = fmaxf(fmaxf(vv[0], vv[1]), fmaxf(vv[2], vv[3]));
      mx = fmaxf(mx, __shfl_xor(mx, 16));
      mx = fmaxf(mx, __shfl_xor(mx, 32));
      float alpha = 1.0f;
      bf16x4 pb = {};
      if (mx > 0.5f * NEG_BIG) {
        const float mnew = fmaxf(mrow, mx);
        alpha = __expf(mrow - mnew);
        float rs = 0.0f;
#pragma unroll
        for (int r = 0; r < 4; r++) {
          const float p = __expf(vv[r] - mnew);  // masked -> exp(-1e30)=0
          pb[r] = (bf16_t)p;
          rs += p;
        }
        rs += __shfl_xor(rs, 16);
        rs += __shfl_xor(rs, 32);
        lrow = lrow * alpha + rs;
        mrow = mnew;
      }
      // ---- rescale O only when some row updated its max
      if (__any(alpha < 1.0f)) {
        float al[4];
#pragma unroll
        for (int rr = 0; rr < 4; rr++) al[rr] = __shfl(alpha, sbase + rr);
#pragma unroll
        for (int dt = 0; dt < 16; dt++) {
#pragma unroll
          for (int rr = 0; rr < 4; rr++) oacc[dt][rr] *= al[rr];
        }
      }
      // ---- O += P.V : x16 MFMA; A=pb (registers), B direct from global vT:
      // vf = V[kv=j*16+quad*4+i][d=half*256+dt*16+l15] = 8B contiguous
      const bf16_t* vrow = vbase + (size_t)l15 * 4096 + j * 16 + quad * 4;
#pragma unroll
      for (int dt = 0; dt < 16; dt++) {
        const bf16x4 vf = *(const bf16x4*)(vrow + (size_t)dt * 16 * 4096);
        oacc[dt] = mfma16(pb, vf, oacc[dt]);
      }
    }
    __syncthreads();  // buf swap + drains the (overlapped) staging
  }

  // ---- epilogue: O / l -> bf16 into this half's 256 columns
  const float linv = (lrow > 0.0f) ? 1.0f / lrow : 0.0f;
  float il[4];
#pragma unroll
  for (int rr = 0; rr < 4; rr++) il[rr] = __shfl(linv, sbase + rr);
#pragma unroll
  for (int rr = 0; rr < 4; rr++) {
    bf16_t* orow =
        o + ((size_t)(b * 4096 + t0 + quad * 4 + rr)) * 512 + half * 256 + l15;
#pragma unroll
    for (int dt = 0; dt < 16; dt++) orow[dt * 16] = (bf16_t)(oacc[dt][rr] * il[rr]);
  }
}

// ---------------------------------------------------------------------------
extern "C" void kernel_launch(void* const* d_in, const int* in_sizes, int n_in,
                              void* d_out, int out_size, void* d_ws, size_t ws_size,
                              hipStream_t stream) {
  const float* x_f = (const float*)d_in[0];   // [4,4096,512] fp32
  const float* wq_f = (const float*)d_in[1];  // [1536,512]   fp32
  const float* wp_f = (const float*)d_in[2];  // [512,512]    fp32
  float* out = (float*)d_out;                 // [4,4096,512] fp32

  // ws (bf16): xb (16MB, reused as attn output) | wqb | wpb | q | k | vT
  bf16_t* xb = (bf16_t*)d_ws;
  bf16_t* wqb = xb + (size_t)16384 * 512;
  bf16_t* wpb = wqb + (size_t)1536 * 512;
  bf16_t* q = wpb + (size_t)512 * 512;
  bf16_t* kk = q + (size_t)16384 * 512;
  bf16_t* vT = kk + (size_t)16384 * 512;

  // 0) convert fp32 inputs -> bf16
  cvt_kernel<<<(16384 * 512) / 1024, 256, 0, stream>>>(x_f, xb);
  cvt_kernel<<<(1536 * 512) / 1024, 256, 0, stream>>>(wq_f, wqb);
  cvt_kernel<<<(512 * 512) / 1024, 256, 0, stream>>>(wp_f, wpb);

  // 1) qkv = x @ Wqkv^T ; v stored transposed (xb dead afterwards)
  gemm_bt_kernel<0><<<128 * 12, 256, 0, stream>>>(xb, wqb, q, kk, vT, nullptr);
  // 2) causal attention -> xb (512 blocks x 256 thr, dbuf-K, V from global)
  attn_kernel<<<512, 256, 0, stream>>>(q, kk, vT, xb);
  // 3) y = attn @ Wproj^T -> fp32 d_out
  gemm_bt_kernel<1><<<128 * 4, 256, 0, stream>>>(xb, wpb, nullptr, nullptr, nullptr, out);
}

// Round 11
// 889.212 us; speedup vs baseline: 1.1243x; 1.1243x over previous
//
#include <hip/hip_runtime.h>
#include <hip/hip_bf16.h>
#include <stdint.h>

typedef __bf16 bf16_t;
typedef __bf16 bf16x4 __attribute__((ext_vector_type(4)));
typedef __bf16 bf16x8 __attribute__((ext_vector_type(8)));
typedef short s16x4 __attribute__((ext_vector_type(4)));
typedef float f32x4 __attribute__((ext_vector_type(4)));

static_assert(sizeof(bf16x8) == 16, "bf16x8 must be 16B");

#define MFMA_BF16(a, b, c) __builtin_amdgcn_mfma_f32_16x16x32_bf16((a), (b), (c), 0, 0, 0)

// 16x16x16 bf16 MFMA (r9/r10 HW-verified: A[m=l15][k=quad*4+i],
// B[k=quad*4+i][n=l15], C/D row=quad*4+r col=l15)
__device__ __forceinline__ f32x4 mfma16(bf16x4 a, bf16x4 b, f32x4 c) {
#if __has_builtin(__builtin_amdgcn_mfma_f32_16x16x16bf16_1k)
  union { bf16x4 h; s16x4 s; } ua, ub;
  ua.h = a;
  ub.h = b;
  return __builtin_amdgcn_mfma_f32_16x16x16bf16_1k(ua.s, ub.s, c, 0, 0, 0);
#else
  f32x4 d = c;
  asm volatile("v_mfma_f32_16x16x16_bf16 %0, %1, %2, %0" : "+v"(d) : "v"(a), "v"(b));
  return d;
#endif
}

typedef const __attribute__((address_space(1))) void* gas_ptr;
typedef __attribute__((address_space(3))) void* las_ptr;

__device__ __forceinline__ void gload_lds16(const void* g, void* l) {
  __builtin_amdgcn_global_load_lds((gas_ptr)g, (las_ptr)l, 16, 0, 0);
}

#define NEG_BIG (-1.0e30f)

// ---------------------------------------------------------------------------
// fp32 -> bf16 convert
// ---------------------------------------------------------------------------
__global__ __launch_bounds__(256) void cvt_kernel(const float* __restrict__ src,
                                                  bf16_t* __restrict__ dst) {
  const int i = (blockIdx.x * 256 + threadIdx.x) * 4;
  const f32x4 v = *(const f32x4*)(src + i);
  bf16x4 o;
  o[0] = (bf16_t)v[0];
  o[1] = (bf16_t)v[1];
  o[2] = (bf16_t)v[2];
  o[3] = (bf16_t)v[3];
  *(bf16x4*)(dst + i) = o;
}

// ---------------------------------------------------------------------------
// GEMM (m97 structure): D[m][n] = sum_k A[m][k] * Bw[n][k]
// MODE 0: qkv epilogue -> q / k row-major (bf16), v transposed to vT[b][d][t]
// MODE 1: final epilogue -> o_f as FP32
// ---------------------------------------------------------------------------
template <int MODE>
__global__ __launch_bounds__(256, 2) void gemm_bt_kernel(
    const bf16_t* __restrict__ A, const bf16_t* __restrict__ Bw,
    bf16_t* __restrict__ o_q, bf16_t* __restrict__ o_k, bf16_t* __restrict__ o_vT,
    float* __restrict__ o_f) {
  constexpr int K = 512;
  __shared__ bf16_t As[128 * 32];
  __shared__ bf16_t Bs[128 * 32];

  const int tid = threadIdx.x;
  const int lane = tid & 63;
  const int wid = tid >> 6;
  const int quad = lane >> 4;
  const int l15 = lane & 15;
  const int wm = wid >> 1;
  const int wn = wid & 1;

  const int mt = blockIdx.x & 127;
  const int nt = blockIdx.x >> 7;
  const int row0 = mt * 128;
  const int col0 = nt * 128;

  f32x4 acc[4][4] = {};

  for (int kt = 0; kt < K; kt += 32) {
    __syncthreads();
#pragma unroll
    for (int rnd = 0; rnd < 2; rnd++) {
      const int e = (rnd * 256 + tid) * 8;
      const int r = e >> 5;
      const int c = e & 31;
      gload_lds16(A + (size_t)(row0 + r) * K + kt + c, As + e);
      gload_lds16(Bw + (size_t)(col0 + r) * K + kt + c, Bs + e);
    }
    __syncthreads();

    bf16x8 af[4], bfr[4];
#pragma unroll
    for (int i = 0; i < 4; i++)
      af[i] = *(const bf16x8*)(As + (wm * 64 + i * 16 + l15) * 32 + quad * 8);
#pragma unroll
    for (int i = 0; i < 4; i++)
      bfr[i] = *(const bf16x8*)(Bs + (wn * 64 + i * 16 + l15) * 32 + quad * 8);
#pragma unroll
    for (int mi = 0; mi < 4; mi++)
#pragma unroll
      for (int ni = 0; ni < 4; ni++)
        acc[mi][ni] = MFMA_BF16(af[mi], bfr[ni], acc[mi][ni]);
  }

#pragma unroll
  for (int mi = 0; mi < 4; mi++) {
    const int row = row0 + wm * 64 + mi * 16 + quad * 4;
#pragma unroll
    for (int ni = 0; ni < 4; ni++) {
      const int col = col0 + wn * 64 + ni * 16 + l15;
#pragma unroll
      for (int r = 0; r < 4; r++) {
        const int rr = row + r;
        if constexpr (MODE == 0) {
          const bf16_t bv = (bf16_t)acc[mi][ni][r];
          if (col < 512) {
            o_q[(size_t)rr * 512 + col] = bv;
          } else if (col < 1024) {
            o_k[(size_t)rr * 512 + (col - 512)] = bv;
          } else {
            const int bb = rr >> 12;
            const int t = rr & 4095;
            o_vT[((size_t)bb * 512 + (col - 1024)) * 4096 + t] = bv;
          }
        } else {
          o_f[(size_t)rr * 512 + col] = acc[mi][ni][r];
        }
      }
    }
  }
}

// ---------------------------------------------------------------------------
// Split-KV flash attention, stage 1 (partials).
// Block (b, s, c): q-strip s (64 rows; wave owns 16 via l15), KV chunk c
// (512 cols). Grid = 4 * sum_s (floor(s/8)+1) = 1152 UNIFORM blocks
// -> ~4.5 blocks/CU offered, 2 resident (VGPR) = 8 waves/CU sustained.
// Inner loop: KV-tile 32, Ks[2][32x512] dbuf (64 KB), ONE barrier/iter,
// S^T = K.Q^T (x32 MFMA, swizzled Ks), per-lane softmax (qrow = l15),
// P in registers -> x16 MFMA PV with V direct from global vT (8B frags).
// Output: unnormalized O partial (bf16) + per-row (m, l) stats.
// ---------------------------------------------------------------------------
__global__ __launch_bounds__(256, 2) void attn_part_kernel(
    const bf16_t* __restrict__ q, const bf16_t* __restrict__ k,
    const bf16_t* __restrict__ vT, bf16_t* __restrict__ partO,
    float2* __restrict__ stats) {
  __shared__ bf16_t Ks[2][32 * 512];  // 64 KB dbuf, chunk-XOR swizzled

  const int tid = threadIdx.x;
  const int lane = tid & 63;
  const int wid = tid >> 6;
  const int quad = lane >> 4;
  const int l15 = lane & 15;

  // decode block -> (b, s, c)
  const int bid = blockIdx.x;
  const int b = bid & 3;
  const int w = bid >> 2;  // 0..287
  int g = 0;
  while (w >= 4 * (g + 1) * (g + 2)) g++;  // group = floor(s/8), 0..7
  const int rem = w - 4 * g * (g + 1);
  const int i = rem / (g + 1);
  const int c = rem - i * (g + 1);
  const int s = 8 * g + i;

  const int t0 = s * 64 + wid * 16;  // this wave's q rows
  const int kv0 = c * 512;           // chunk start

  const float scale = 0.044194173824159216f;  // 1/sqrt(512)
  const bf16_t* kbase = k + ((size_t)b * 4096 + kv0) * 512;
  const bf16_t* vbase = vT + (size_t)b * 512 * 4096;

  // Q B-fragments: lane holds q[t0+l15][kk*32+quad*8 .. +7]
  bf16x8 qf[16];
  {
    const bf16_t* qp = q + ((size_t)(b * 4096 + t0 + l15)) * 512 + quad * 8;
#pragma unroll
    for (int kk = 0; kk < 16; kk++) qf[kk] = *(const bf16x8*)(qp + kk * 32);
  }

  f32x4 oacc[32] = {};  // oacc[dt][rr] = O[qrow=quad*4+rr][d=dt*16+l15]
  float mrow = NEG_BIG, lrow = 0.0f;

  // wave's last tile with any visible kv (non-diag chunks: 15)
  const int jcw = min(15, (t0 + 15 - kv0) >> 5);

  // prologue: stage tile 0 (32 KB = 8 rounds x 256 thr x 16B)
#pragma unroll
  for (int rnd = 0; rnd < 8; rnd++) {
    const int ch = rnd * 256 + tid;
    const int kr = ch >> 6;
    const int gc = (ch & 63) ^ (kr & 7);
    gload_lds16(kbase + (size_t)kr * 512 + gc * 8, &Ks[0][ch * 8]);
  }
  __syncthreads();

  const int sbase = (lane & 48) + ((lane & 48) >> 2);  // lane w/ l15=quad*4

  for (int j = 0; j < 16; j++) {
    const int buf = j & 1;
    // issue next tile's staging first (drained by end-of-iter barrier)
    if (j < 15) {
      const bf16_t* kg = kbase + (size_t)(j + 1) * 32 * 512;
#pragma unroll
      for (int rnd = 0; rnd < 8; rnd++) {
        const int ch = rnd * 256 + tid;
        const int kr = ch >> 6;
        const int gc = (ch & 63) ^ (kr & 7);
        gload_lds16(kg + (size_t)kr * 512 + gc * 8, &Ks[buf ^ 1][ch * 8]);
      }
    }

    if (j <= jcw) {
      // ---- S^T[kv32 x qrow16] = K . Q^T, two 16-kv groups
      f32x4 sT0 = {}, sT1 = {};
      const bf16_t* krow0 = &Ks[buf][l15 * 512];
      const bf16_t* krow1 = &Ks[buf][(16 + l15) * 512];
      const int sw = l15 & 7;
#pragma unroll
      for (int kk = 0; kk < 16; kk++) {
        const int co = ((kk * 4 + quad) ^ sw) * 8;
        const bf16x8 kf0 = *(const bf16x8*)(krow0 + co);
        const bf16x8 kf1 = *(const bf16x8*)(krow1 + co);
        sT0 = MFMA_BF16(kf0, qf[kk], sT0);
        sT1 = MFMA_BF16(kf1, qf[kk], sT1);
      }
      // ---- mask + inf-free online softmax (state per qrow = l15)
      const int qr = t0 + l15;
      const int kvg = kv0 + j * 32 + quad * 4;
      float vv0[4], vv1[4];
#pragma unroll
      for (int r = 0; r < 4; r++) {
        vv0[r] = (kvg + r <= qr) ? sT0[r] * scale : NEG_BIG;
        vv1[r] = (kvg + 16 + r <= qr) ? sT1[r] * scale : NEG_BIG;
      }
      float mx = fmaxf(fmaxf(fmaxf(vv0[0], vv0[1]), fmaxf(vv0[2], vv0[3])),
                       fmaxf(fmaxf(vv1[0], vv1[1]), fmaxf(vv1[2], vv1[3])));
      mx = fmaxf(mx, __shfl_xor(mx, 16));
      mx = fmaxf(mx, __shfl_xor(mx, 32));
      float alpha = 1.0f;
      bf16x4 pb0 = {}, pb1 = {};
      if (mx > 0.5f * NEG_BIG) {
        const float mnew = fmaxf(mrow, mx);
        alpha = __expf(mrow - mnew);
        float rs = 0.0f;
#pragma unroll
        for (int r = 0; r < 4; r++) {
          const float p0 = __expf(vv0[r] - mnew);
          const float p1 = __expf(vv1[r] - mnew);
          pb0[r] = (bf16_t)p0;
          pb1[r] = (bf16_t)p1;
          rs += p0 + p1;
        }
        rs += __shfl_xor(rs, 16);
        rs += __shfl_xor(rs, 32);
        lrow = lrow * alpha + rs;
        mrow = mnew;
      }
      if (__any(alpha < 1.0f)) {
        float al[4];
#pragma unroll
        for (int rr = 0; rr < 4; rr++) al[rr] = __shfl(alpha, sbase + rr);
#pragma unroll
        for (int dt = 0; dt < 32; dt++) {
#pragma unroll
          for (int rr = 0; rr < 4; rr++) oacc[dt][rr] *= al[rr];
        }
      }
      // ---- O += P.V (x16 MFMA x2 groups); V direct from global vT:
      // vf = V[kv=kvg+i (+16)][d=dt*16+l15], 8B contiguous per lane
      const bf16_t* vrow = vbase + (size_t)l15 * 4096 + kv0 + j * 32 + quad * 4;
#pragma unroll
      for (int dt = 0; dt < 32; dt++) {
        const bf16_t* vp = vrow + (size_t)dt * 16 * 4096;
        const bf16x4 vf0 = *(const bf16x4*)(vp);
        const bf16x4 vf1 = *(const bf16x4*)(vp + 16);
        oacc[dt] = mfma16(pb0, vf0, oacc[dt]);
        oacc[dt] = mfma16(pb1, vf1, oacc[dt]);
      }
    }
    __syncthreads();  // buf swap; drains (overlapped) staging
  }

  // ---- write unnormalized partial + stats
  bf16_t* pbase = partO + (size_t)bid * 64 * 512;
#pragma unroll
  for (int rr = 0; rr < 4; rr++) {
    bf16_t* prow = pbase + (size_t)(wid * 16 + quad * 4 + rr) * 512 + l15;
#pragma unroll
    for (int dt = 0; dt < 32; dt++) prow[dt * 16] = (bf16_t)(oacc[dt][rr]);
  }
  if (quad == 0) stats[(size_t)bid * 64 + wid * 16 + l15] = make_float2(mrow, lrow);
}

// ---------------------------------------------------------------------------
// Split-KV flash attention, stage 2 (combine). Block = (b, s): merge nc
// chunk partials with softmax-stat weighting, write normalized bf16 to o.
// ---------------------------------------------------------------------------
__global__ __launch_bounds__(256) void attn_combine_kernel(
    const bf16_t* __restrict__ partO, const float2* __restrict__ stats,
    bf16_t* __restrict__ o) {
  const int b = blockIdx.x & 3;
  const int s = blockIdx.x >> 2;
  const int g = s >> 3;
  const int nc = g + 1;
  const int w0 = 4 * g * (g + 1) + (s & 7) * (g + 1);  // first chunk's w

  __shared__ float wgt[8][64];
  __shared__ float linv[64];

  const int tid = threadIdx.x;
  if (tid < 64) {
    float mc[8], lc[8];
    float M = NEG_BIG;
    for (int cc = 0; cc < nc; cc++) {
      const float2 ml = stats[(size_t)(((w0 + cc) << 2) | b) * 64 + tid];
      mc[cc] = ml.x;
      lc[cc] = ml.y;
      M = fmaxf(M, ml.x);
    }
    float L = 0.0f;
    for (int cc = 0; cc < nc; cc++) {
      const float wv = __expf(mc[cc] - M);
      wgt[cc][tid] = wv;
      L += wv * lc[cc];
    }
    linv[tid] = (L > 0.0f) ? 1.0f / L : 0.0f;
  }
  __syncthreads();

#pragma unroll
  for (int it = 0; it < 16; it++) {
    const int idx = it * 256 + tid;  // 4096 bf16x8 groups: 64 rows x 64
    const int row = idx >> 6;
    const int d8 = (idx & 63) * 8;
    float acc[8] = {};
    for (int cc = 0; cc < nc; cc++) {
      const bf16x8 p = *(const bf16x8*)(partO +
          (size_t)(((w0 + cc) << 2) | b) * 32768 + (size_t)row * 512 + d8);
      const float wv = wgt[cc][row];
#pragma unroll
      for (int e = 0; e < 8; e++) acc[e] += wv * (float)p[e];
    }
    const float li = linv[row];
    bf16x8 ov;
#pragma unroll
    for (int e = 0; e < 8; e++) ov[e] = (bf16_t)(acc[e] * li);
    *(bf16x8*)(o + ((size_t)(b * 4096 + s * 64 + row)) * 512 + d8) = ov;
  }
}

// ---------------------------------------------------------------------------
extern "C" void kernel_launch(void* const* d_in, const int* in_sizes, int n_in,
                              void* d_out, int out_size, void* d_ws, size_t ws_size,
                              hipStream_t stream) {
  const float* x_f = (const float*)d_in[0];   // [4,4096,512] fp32
  const float* wq_f = (const float*)d_in[1];  // [1536,512]   fp32
  const float* wp_f = (const float*)d_in[2];  // [512,512]    fp32
  float* out = (float*)d_out;                 // [4,4096,512] fp32

  // ws (bf16 unless noted): xb | wqb | wpb | q | k | vT | partO | stats(f32x2)
  bf16_t* xb = (bf16_t*)d_ws;                      // 16 MB (attn output)
  bf16_t* wqb = xb + (size_t)16384 * 512;          // 1.5 MB
  bf16_t* wpb = wqb + (size_t)1536 * 512;          // 0.5 MB
  bf16_t* q = wpb + (size_t)512 * 512;             // 16 MB
  bf16_t* kk = q + (size_t)16384 * 512;            // 16 MB
  bf16_t* vT = kk + (size_t)16384 * 512;           // 16 MB
  bf16_t* partO = vT + (size_t)16384 * 512;        // 1152*64*512*2 = 75.5 MB
  float2* stats = (float2*)(partO + (size_t)1152 * 64 * 512);  // 0.6 MB

  // 0) convert fp32 inputs -> bf16
  cvt_kernel<<<(16384 * 512) / 1024, 256, 0, stream>>>(x_f, xb);
  cvt_kernel<<<(1536 * 512) / 1024, 256, 0, stream>>>(wq_f, wqb);
  cvt_kernel<<<(512 * 512) / 1024, 256, 0, stream>>>(wp_f, wpb);

  // 1) qkv = x @ Wqkv^T ; v stored transposed (xb dead afterwards)
  gemm_bt_kernel<0><<<128 * 12, 256, 0, stream>>>(xb, wqb, q, kk, vT, nullptr);
  // 2a) split-KV attention partials (1152 uniform blocks)
  attn_part_kernel<<<1152, 256, 0, stream>>>(q, kk, vT, partO, stats);
  // 2b) combine partials -> xb
  attn_combine_kernel<<<256, 256, 0, stream>>>(partO, stats, xb);
  // 3) y = attn @ Wproj^T -> fp32 d_out
  gemm_bt_kernel<1><<<128 * 4, 256, 0, stream>>>(xb, wpb, nullptr, nullptr, nullptr, out);
}

// Round 12
// 489.985 us; speedup vs baseline: 2.0403x; 1.8148x over previous
//
#include <hip/hip_runtime.h>
#include <hip/hip_bf16.h>
#include <stdint.h>

typedef __bf16 bf16_t;
typedef __bf16 bf16x4 __attribute__((ext_vector_type(4)));
typedef __bf16 bf16x8 __attribute__((ext_vector_type(8)));
typedef short s16x4 __attribute__((ext_vector_type(4)));
typedef float f32x4 __attribute__((ext_vector_type(4)));

static_assert(sizeof(bf16x8) == 16, "bf16x8 must be 16B");

#define MFMA_BF16(a, b, c) __builtin_amdgcn_mfma_f32_16x16x32_bf16((a), (b), (c), 0, 0, 0)

// 16x16x16 bf16 MFMA (r9/r10 HW-verified: A[m=l15][k=quad*4+i],
// B[k=quad*4+i][n=l15], C/D row=quad*4+r col=l15)
__device__ __forceinline__ f32x4 mfma16(bf16x4 a, bf16x4 b, f32x4 c) {
#if __has_builtin(__builtin_amdgcn_mfma_f32_16x16x16bf16_1k)
  union { bf16x4 h; s16x4 s; } ua, ub;
  ua.h = a;
  ub.h = b;
  return __builtin_amdgcn_mfma_f32_16x16x16bf16_1k(ua.s, ub.s, c, 0, 0, 0);
#else
  f32x4 d = c;
  asm volatile("v_mfma_f32_16x16x16_bf16 %0, %1, %2, %0" : "+v"(d) : "v"(a), "v"(b));
  return d;
#endif
}

typedef const __attribute__((address_space(1))) void* gas_ptr;
typedef __attribute__((address_space(3))) void* las_ptr;

__device__ __forceinline__ void gload_lds16(const void* g, void* l) {
  __builtin_amdgcn_global_load_lds((gas_ptr)g, (las_ptr)l, 16, 0, 0);
}

#define NEG_BIG (-1.0e30f)

// ---------------------------------------------------------------------------
// fp32 -> bf16 convert
// ---------------------------------------------------------------------------
__global__ __launch_bounds__(256) void cvt_kernel(const float* __restrict__ src,
                                                  bf16_t* __restrict__ dst) {
  const int i = (blockIdx.x * 256 + threadIdx.x) * 4;
  const f32x4 v = *(const f32x4*)(src + i);
  bf16x4 o;
  o[0] = (bf16_t)v[0];
  o[1] = (bf16_t)v[1];
  o[2] = (bf16_t)v[2];
  o[3] = (bf16_t)v[3];
  *(bf16x4*)(dst + i) = o;
}

// ---------------------------------------------------------------------------
// GEMM (m97 structure): D[m][n] = sum_k A[m][k] * Bw[n][k]
// MODE 0: qkv epilogue -> q / k row-major (bf16), v transposed to vT[b][d][t]
// MODE 1: final epilogue -> o_f as FP32
// ---------------------------------------------------------------------------
template <int MODE>
__global__ __launch_bounds__(256, 2) void gemm_bt_kernel(
    const bf16_t* __restrict__ A, const bf16_t* __restrict__ Bw,
    bf16_t* __restrict__ o_q, bf16_t* __restrict__ o_k, bf16_t* __restrict__ o_vT,
    float* __restrict__ o_f) {
  constexpr int K = 512;
  __shared__ bf16_t As[128 * 32];
  __shared__ bf16_t Bs[128 * 32];

  const int tid = threadIdx.x;
  const int lane = tid & 63;
  const int wid = tid >> 6;
  const int quad = lane >> 4;
  const int l15 = lane & 15;
  const int wm = wid >> 1;
  const int wn = wid & 1;

  const int mt = blockIdx.x & 127;
  const int nt = blockIdx.x >> 7;
  const int row0 = mt * 128;
  const int col0 = nt * 128;

  f32x4 acc[4][4] = {};

  for (int kt = 0; kt < K; kt += 32) {
    __syncthreads();
#pragma unroll
    for (int rnd = 0; rnd < 2; rnd++) {
      const int e = (rnd * 256 + tid) * 8;
      const int r = e >> 5;
      const int c = e & 31;
      gload_lds16(A + (size_t)(row0 + r) * K + kt + c, As + e);
      gload_lds16(Bw + (size_t)(col0 + r) * K + kt + c, Bs + e);
    }
    __syncthreads();

    bf16x8 af[4], bfr[4];
#pragma unroll
    for (int i = 0; i < 4; i++)
      af[i] = *(const bf16x8*)(As + (wm * 64 + i * 16 + l15) * 32 + quad * 8);
#pragma unroll
    for (int i = 0; i < 4; i++)
      bfr[i] = *(const bf16x8*)(Bs + (wn * 64 + i * 16 + l15) * 32 + quad * 8);
#pragma unroll
    for (int mi = 0; mi < 4; mi++)
#pragma unroll
      for (int ni = 0; ni < 4; ni++)
        acc[mi][ni] = MFMA_BF16(af[mi], bfr[ni], acc[mi][ni]);
  }

#pragma unroll
  for (int mi = 0; mi < 4; mi++) {
    const int row = row0 + wm * 64 + mi * 16 + quad * 4;
#pragma unroll
    for (int ni = 0; ni < 4; ni++) {
      const int col = col0 + wn * 64 + ni * 16 + l15;
#pragma unroll
      for (int r = 0; r < 4; r++) {
        const int rr = row + r;
        if constexpr (MODE == 0) {
          const bf16_t bv = (bf16_t)acc[mi][ni][r];
          if (col < 512) {
            o_q[(size_t)rr * 512 + col] = bv;
          } else if (col < 1024) {
            o_k[(size_t)rr * 512 + (col - 512)] = bv;
          } else {
            const int bb = rr >> 12;
            const int t = rr & 4095;
            o_vT[((size_t)bb * 512 + (col - 1024)) * 4096 + t] = bv;
          }
        } else {
          o_f[(size_t)rr * 512 + col] = acc[mi][ni][r];
        }
      }
    }
  }
}

// ---------------------------------------------------------------------------
// Split-KV flash attention stage 1, PHASE-SPLIT version.
// Block (b, s, c, half): 64 q-rows (wave owns 16 via l15), 512-kv chunk,
// 256-d output half. Grid = 2304 uniform blocks.
//  Phase 1 (pure GEMM): S^T[512kv x 16q] = K.Q^T, 16 d-iters; per iter stage
//    K-slice [512kv x 32d] (32 KB, double-XOR swizzle -> 2-way banks), then
//    32 independent-accumulator x32 MFMAs per wave. No softmax inside.
//  Phase 2 (registers only): single-pass masked softmax over S^T; per-lane
//    all 128 values share qrow=l15; 2 shfls; P -> bf16x4 pb[32] (A-layout).
//  Phase 3 (pure GEMM): O[16q x 256d] = P.V, 8 kv-iters; per iter stage
//    V^T-slice [256d x 64kv] (32 KB, XOR swizzle -> 2-way), 64 x16 MFMAs.
// Diagonal chunks skip dead kv-tiles via wave-uniform mmax.
// Output: unnormalized bf16 partial + (m, l) stats (half 0 writes stats).
// ---------------------------------------------------------------------------
__global__ __launch_bounds__(256, 2) void attn_part_kernel(
    const bf16_t* __restrict__ q, const bf16_t* __restrict__ k,
    const bf16_t* __restrict__ vT, bf16_t* __restrict__ partO,
    float2* __restrict__ stats) {
  __shared__ bf16_t SB[16384];  // 32 KB, shared by phase 1 and phase 3

  const int tid = threadIdx.x;
  const int lane = tid & 63;
  const int wid = tid >> 6;
  const int quad = lane >> 4;
  const int l15 = lane & 15;

  const int bid = blockIdx.x;
  const int b = bid & 3;
  const int half = (bid >> 2) & 1;
  const int w = bid >> 3;  // 0..287
  int g = 0;
  while (w >= 4 * (g + 1) * (g + 2)) g++;  // strip group = s>>3
  const int rem = w - 4 * g * (g + 1);
  const int i = rem / (g + 1);
  const int c = rem - i * (g + 1);
  const int s = 8 * g + i;

  const int t0w = s * 64 + wid * 16;  // this wave's q rows
  const int kv0 = c * 512;
  const int mmax = min(31, (t0w + 15 - kv0) >> 4);  // wave-uniform
  const int kvtmax = mmax >> 2;

  const float scale = 0.044194173824159216f;  // 1/sqrt(512)
  const bf16_t* kbase = k + ((size_t)b * 4096 + kv0) * 512;
  const bf16_t* vbase = vT + ((size_t)(b * 512 + half * 256)) * 4096 + kv0;

  // Q B-frags: qf[kt] = Q[qrow=l15][kt*32 + quad*8 .. +7]
  bf16x8 qf[16];
  {
    const bf16_t* qp = q + ((size_t)(b * 4096 + t0w + l15)) * 512 + quad * 8;
#pragma unroll
    for (int kk = 0; kk < 16; kk++) qf[kk] = *(const bf16x8*)(qp + kk * 32);
  }

  // ---- Phase 1: S^T accumulate -------------------------------------------
  f32x4 Sacc[32];
#pragma unroll
  for (int m = 0; m < 32; m++) Sacc[m] = f32x4{0.f, 0.f, 0.f, 0.f};

  // per-lane A-frag base (elements); m-stride = 512 elements.
  // Layout: chunk(row,c) at g4*16 + (c^(g4&3))*4 + (row&3), g4=row>>2.
  const int abase =
      ((l15 >> 2) * 16 + (quad ^ ((l15 >> 2) & 3)) * 4 + (l15 & 3)) * 8;

#pragma unroll
  for (int kt = 0; kt < 16; kt++) {
    __syncthreads();
#pragma unroll
    for (int rnd = 0; rnd < 8; rnd++) {
      const int ch = rnd * 256 + tid;
      const int g4 = ch >> 4;
      const int w16 = ch & 15;
      const int cg = (w16 >> 2) ^ (g4 & 3);
      const int row = g4 * 4 + (w16 & 3);
      gload_lds16(kbase + (size_t)row * 512 + kt * 32 + cg * 8, SB + ch * 8);
    }
    __syncthreads();
#pragma unroll
    for (int m = 0; m < 32; m++) {
      if (m <= mmax) {  // wave-uniform
        const bf16x8 kf = *(const bf16x8*)(SB + abase + m * 512);
        Sacc[m] = MFMA_BF16(kf, qf[kt], Sacc[m]);
      }
    }
  }

  // ---- Phase 2: masked softmax (per-lane: all values share qrow=l15) -----
  const int qr = t0w + l15;
  float mx = NEG_BIG;
#pragma unroll
  for (int m = 0; m < 32; m++) {
    if (m <= mmax) {
#pragma unroll
      for (int r = 0; r < 4; r++) {
        const int kv = kv0 + m * 16 + quad * 4 + r;
        const float vvv = (kv <= qr) ? Sacc[m][r] : NEG_BIG;
        Sacc[m][r] = vvv;
        mx = fmaxf(mx, vvv);
      }
    }
  }
  mx = fmaxf(mx, __shfl_xor(mx, 16));
  mx = fmaxf(mx, __shfl_xor(mx, 32));  // finite: kv0 <= qr always

  float lrow = 0.0f;
  bf16x4 pb[32];
#pragma unroll
  for (int m = 0; m < 32; m++) {
    bf16x4 pv = {};
    if (m <= mmax) {
#pragma unroll
      for (int r = 0; r < 4; r++) {
        const float p = __expf((Sacc[m][r] - mx) * scale);  // masked -> 0
        pv[r] = (bf16_t)p;
        lrow += p;
      }
    }
    pb[m] = pv;
  }
  lrow += __shfl_xor(lrow, 16);
  lrow += __shfl_xor(lrow, 32);

  if (half == 0 && quad == 0)
    stats[((size_t)w * 4 + b) * 64 + wid * 16 + l15] =
        make_float2(mx * scale, lrow);

  // ---- Phase 3: O = P.V (pure GEMM over kv) ------------------------------
  f32x4 Oacc[16];
#pragma unroll
  for (int dt = 0; dt < 16; dt++) Oacc[dt] = f32x4{0.f, 0.f, 0.f, 0.f};

  const int l64 = l15 * 64;
  const int qh = quad >> 1;
  const int ql = (quad & 1) * 4;
  const int s7 = l15 & 7;

#pragma unroll
  for (int kvt = 0; kvt < 8; kvt++) {
    __syncthreads();
    // stage V^T slice [256d x 64kv] from vT, XOR-swizzled 16B chunks
#pragma unroll
    for (int rnd = 0; rnd < 8; rnd++) {
      const int ch = rnd * 256 + tid;
      const int d = ch >> 3;
      const int cg = (ch & 7) ^ (d & 7);
      gload_lds16(vbase + (size_t)d * 4096 + kvt * 64 + cg * 8, SB + ch * 8);
    }
    __syncthreads();
    if (kvt <= kvtmax) {  // wave-uniform
#pragma unroll
      for (int dt = 0; dt < 16; dt++) {
#pragma unroll
        for (int gg = 0; gg < 4; gg++) {
          const bf16x4 vf = *(const bf16x4*)(
              SB + dt * 1024 + l64 + (((gg * 2 + qh) ^ s7) << 3) + ql);
          Oacc[dt] = mfma16(pb[kvt * 4 + gg], vf, Oacc[dt]);
        }
      }
    }
  }

  // ---- write unnormalized partial [64 x 256] -----------------------------
  bf16_t* pbase = partO + (size_t)bid * 16384;
#pragma unroll
  for (int rr = 0; rr < 4; rr++) {
    bf16_t* prow = pbase + (size_t)(wid * 16 + quad * 4 + rr) * 256 + l15;
#pragma unroll
    for (int dt = 0; dt < 16; dt++) prow[dt * 16] = (bf16_t)Oacc[dt][rr];
  }
}

// ---------------------------------------------------------------------------
// Stage 2: combine chunk partials per (b, s) with softmax-stat weighting.
// ---------------------------------------------------------------------------
__global__ __launch_bounds__(256) void attn_combine_kernel(
    const bf16_t* __restrict__ partO, const float2* __restrict__ stats,
    bf16_t* __restrict__ o) {
  const int b = blockIdx.x & 3;
  const int s = blockIdx.x >> 2;
  const int g = s >> 3;
  const int nc = g + 1;
  const int w0 = 4 * g * (g + 1) + (s & 7) * (g + 1);

  __shared__ float wgt[8][64];
  __shared__ float linv[64];

  const int tid = threadIdx.x;
  if (tid < 64) {
    float mc[8], lc[8];
    float M = NEG_BIG;
    for (int cc = 0; cc < nc; cc++) {
      const float2 ml = stats[((size_t)(w0 + cc) * 4 + b) * 64 + tid];
      mc[cc] = ml.x;
      lc[cc] = ml.y;
      M = fmaxf(M, ml.x);
    }
    float L = 0.0f;
    for (int cc = 0; cc < nc; cc++) {
      const float wv = __expf(mc[cc] - M);
      wgt[cc][tid] = wv;
      L += wv * lc[cc];
    }
    linv[tid] = (L > 0.0f) ? 1.0f / L : 0.0f;
  }
  __syncthreads();

#pragma unroll
  for (int it = 0; it < 16; it++) {
    const int idx = it * 256 + tid;  // 64 rows x 64 bf16x8 groups
    const int row = idx >> 6;
    const int d8 = (idx & 63) * 8;
    const int h = d8 >> 8;
    const int dl = d8 & 255;
    float acc[8] = {};
    for (int cc = 0; cc < nc; cc++) {
      const int bidc = ((w0 + cc) << 3) | (h << 2) | b;
      const bf16x8 p = *(const bf16x8*)(partO + (size_t)bidc * 16384 +
                                        (size_t)row * 256 + dl);
      const float wv = wgt[cc][row];
#pragma unroll
      for (int e = 0; e < 8; e++) acc[e] += wv * (float)p[e];
    }
    const float li = linv[row];
    bf16x8 ov;
#pragma unroll
    for (int e = 0; e < 8; e++) ov[e] = (bf16_t)(acc[e] * li);
    *(bf16x8*)(o + ((size_t)(b * 4096 + s * 64 + row)) * 512 + d8) = ov;
  }
}

// ---------------------------------------------------------------------------
extern "C" void kernel_launch(void* const* d_in, const int* in_sizes, int n_in,
                              void* d_out, int out_size, void* d_ws, size_t ws_size,
                              hipStream_t stream) {
  const float* x_f = (const float*)d_in[0];   // [4,4096,512] fp32
  const float* wq_f = (const float*)d_in[1];  // [1536,512]   fp32
  const float* wp_f = (const float*)d_in[2];  // [512,512]    fp32
  float* out = (float*)d_out;                 // [4,4096,512] fp32

  // ws (bf16 unless noted): xb | wqb | wpb | q | k | vT | partO | stats
  bf16_t* xb = (bf16_t*)d_ws;                      // 16 MB (attn output)
  bf16_t* wqb = xb + (size_t)16384 * 512;          // 1.5 MB
  bf16_t* wpb = wqb + (size_t)1536 * 512;          // 0.5 MB
  bf16_t* q = wpb + (size_t)512 * 512;             // 16 MB
  bf16_t* kk = q + (size_t)16384 * 512;            // 16 MB
  bf16_t* vT = kk + (size_t)16384 * 512;           // 16 MB
  bf16_t* partO = vT + (size_t)16384 * 512;        // 2304*16384*2 = 75.5 MB
  float2* stats = (float2*)(partO + (size_t)2304 * 16384);  // 0.6 MB

  // 0) convert fp32 inputs -> bf16
  cvt_kernel<<<(16384 * 512) / 1024, 256, 0, stream>>>(x_f, xb);
  cvt_kernel<<<(1536 * 512) / 1024, 256, 0, stream>>>(wq_f, wqb);
  cvt_kernel<<<(512 * 512) / 1024, 256, 0, stream>>>(wp_f, wpb);

  // 1) qkv = x @ Wqkv^T ; v stored transposed (xb dead afterwards)
  gemm_bt_kernel<0><<<128 * 12, 256, 0, stream>>>(xb, wqb, q, kk, vT, nullptr);
  // 2a) phase-split attention partials (2304 uniform blocks)
  attn_part_kernel<<<2304, 256, 0, stream>>>(q, kk, vT, partO, stats);
  // 2b) combine partials -> xb
  attn_combine_kernel<<<256, 256, 0, stream>>>(partO, stats, xb);
  // 3) y = attn @ Wproj^T -> fp32 d_out
  gemm_bt_kernel<1><<<128 * 4, 256, 0, stream>>>(xb, wpb, nullptr, nullptr, nullptr, out);
}